// Round 1
// baseline (173.365 us; speedup 1.0000x reference)
//
#include <hip/hip_runtime.h>
#include <math.h>

#define HW 1024
#define PLANE (1024 * 1024)
#define MAXCELL 182  // largest gr*gc over n in {20,30,40,65,80,95,125,150,175}

// ws layout (float units):
// [0..8)     csum per batch (float, zeroed each call via hipMemsetAsync)
// [8..32)    packed gr|gc<<8 ints per (batch,map) - 24 entries
// [32..4400) cell means: 8 batches * 3 maps * 182 cells
// [8192 ..)  staged channel-mean image (8*1024*1024 floats) if ws_size permits

__device__ __forceinline__ int wave_reduce_int(int v) {
#pragma unroll
    for (int off = 32; off > 0; off >>= 1) v += __shfl_down(v, off, 64);
    return v;
}
__device__ __forceinline__ float wave_reduce_f(float v) {
#pragma unroll
    for (int off = 32; off > 0; off >>= 1) v += __shfl_down(v, off, 64);
    return v;
}

// Kernel 1: per (batch,row): grayscale index squared-diff partial sums (-> complexity)
// and optional staging of channel-mean image into workspace.
__global__ __launch_bounds__(256) void k_gray(const float* __restrict__ img,
                                              float* __restrict__ csum,
                                              float* __restrict__ stage,
                                              int do_stage) {
    const int row = blockIdx.x;
    const int b = blockIdx.y;
    const int tid = threadIdx.x;
    const int col = tid << 2;

    const float* base = img + (size_t)b * (3 * PLANE) + row * HW + col;
    const float4 r4 = *(const float4*)(base);
    const float4 g4 = *(const float4*)(base + PLANE);
    const float4 b4 = *(const float4*)(base + 2 * PLANE);

    float gray0 = 0.299f * r4.x + 0.587f * g4.x + 0.114f * b4.x;
    float gray1 = 0.299f * r4.y + 0.587f * g4.y + 0.114f * b4.y;
    float gray2 = 0.299f * r4.z + 0.587f * g4.z + 0.114f * b4.z;
    float gray3 = 0.299f * r4.w + 0.587f * g4.w + 0.114f * b4.w;

    int gi0 = min(max((int)(gray0 * 255.0f), 0), 255);
    int gi1 = min(max((int)(gray1 * 255.0f), 0), 255);
    int gi2 = min(max((int)(gray2 * 255.0f), 0), 255);
    int gi3 = min(max((int)(gray3 * 255.0f), 0), 255);

    if (do_stage) {
        float4 cm;
        cm.x = (r4.x + g4.x + b4.x) * (1.0f / 3.0f);
        cm.y = (r4.y + g4.y + b4.y) * (1.0f / 3.0f);
        cm.z = (r4.z + g4.z + b4.z) * (1.0f / 3.0f);
        cm.w = (r4.w + g4.w + b4.w) * (1.0f / 3.0f);
        *(float4*)(stage + ((size_t)b << 20) + row * HW + col) = cm;
    }

    __shared__ int gfirst[256];
    gfirst[tid] = gi0;
    __syncthreads();

    int d0 = gi0 - gi1, d1 = gi1 - gi2, d2 = gi2 - gi3;
    int p = d0 * d0 + d1 * d1 + d2 * d2;
    if (tid < 255) {
        int d3 = gi3 - gfirst[tid + 1];
        p += d3 * d3;
    }

    p = wave_reduce_int(p);
    __shared__ int wsum[4];
    const int lane = tid & 63, w = tid >> 6;
    if (lane == 0) wsum[w] = p;
    __syncthreads();
    if (tid == 0) {
        atomicAdd(&csum[b], (float)(wsum[0] + wsum[1] + wsum[2] + wsum[3]));
    }
}

// Kernel 2: finalize complexity, pick tier, emit cluster_sets (as float32) and
// packed grid geometry per (batch, map).
__global__ void k_finalize(const float* __restrict__ csum,
                           float* __restrict__ out,
                           int* __restrict__ grgc) {
    const int t = threadIdx.x;
    if (t >= 8) return;
    const size_t OFFC = (size_t)8 * 3 * PLANE;
    float cv = csum[t] * (1.0f / (1024.0f * 1023.0f));
    out[OFFC + t] = cv;
    int tier = (cv < 50.0f) ? 0 : ((cv < 150.0f) ? 1 : 2);
    const int BASEv[3] = {30, 80, 150};
    const int INCRv[3] = {10, 15, 25};
    int k = BASEv[tier], d = INCRv[tier];
#pragma unroll
    for (int j = 0; j < 3; ++j) {
        int n = k + (j - 1) * d;
        out[OFFC + 8 + t * 3 + j] = (float)n;  // int32 ref values, float32 buffer
        int gr = (int)floor(sqrt((double)n) + 0.5);  // Python round(sqrt(n)); no .5 ties
        if (gr < 1) gr = 1;
        int gc = (n + gr - 1) / gr;  // ceil(n/gr)
        grgc[t * 3 + j] = gr | (gc << 8);
    }
}

// Kernel 3: one block per (cell, map, batch): mean of channel-mean over the
// cell's rectangle. Row-cell i covers rows [ceil(i*H/gr), ceil((i+1)*H/gr)).
__global__ __launch_bounds__(256) void k_cellmean(const float* __restrict__ img,
                                                  const float* __restrict__ stage,
                                                  const int* __restrict__ grgc,
                                                  float* __restrict__ cellmean,
                                                  int do_stage) {
    const int cell = blockIdx.x, jm = blockIdx.y, b = blockIdx.z;
    const int pk = grgc[b * 3 + jm];
    const int gr = pk & 255, gc = pk >> 8;
    if (cell >= gr * gc) return;
    const int ci = cell / gc, cj = cell - ci * gc;
    const int r0 = (ci * HW + gr - 1) / gr, r1 = ((ci + 1) * HW + gr - 1) / gr;
    const int c0 = (cj * HW + gc - 1) / gc, c1 = ((cj + 1) * HW + gc - 1) / gc;

    const int tid = threadIdx.x;
    const int tx = tid & 63, ty = tid >> 6;
    float s = 0.0f;
    if (do_stage) {
        const float* src = stage + ((size_t)b << 20);
        for (int r = r0 + ty; r < r1; r += 4)
            for (int c = c0 + tx; c < c1; c += 64) s += src[r * HW + c];
    } else {
        const float* src = img + (size_t)b * (3 * PLANE);
        for (int r = r0 + ty; r < r1; r += 4)
            for (int c = c0 + tx; c < c1; c += 64) {
                int idx = r * HW + c;
                s += (src[idx] + src[idx + PLANE] + src[idx + 2 * PLANE]) * (1.0f / 3.0f);
            }
    }
    s = wave_reduce_f(s);
    __shared__ float sw[4];
    const int lane = tid & 63, w = tid >> 6;
    if (lane == 0) sw[w] = s;
    __syncthreads();
    if (tid == 0) {
        float tot = sw[0] + sw[1] + sw[2] + sw[3];
        float area = (float)((r1 - r0) * (c1 - c0));
        cellmean[(b * 3 + jm) * MAXCELL + cell] = tot / area;
    }
}

// Kernel 4: fill saliency output; each thread writes a float4 of one row.
__global__ __launch_bounds__(256) void k_fill(const int* __restrict__ grgc,
                                              const float* __restrict__ cellmean,
                                              float* __restrict__ out) {
    const int row = blockIdx.x, jm = blockIdx.y, b = blockIdx.z;
    const int tid = threadIdx.x;
    const int pk = grgc[b * 3 + jm];
    const int gr = pk & 255, gc = pk >> 8;
    const int rc = (row * gr) >> 10;  // (row*gr)/1024
    const float* cm = cellmean + (b * 3 + jm) * MAXCELL + rc * gc;
    const int col = tid << 2;
    float4 o;
    o.x = cm[(col * gc) >> 10];
    o.y = cm[((col + 1) * gc) >> 10];
    o.z = cm[((col + 2) * gc) >> 10];
    o.w = cm[((col + 3) * gc) >> 10];
    *(float4*)(out + ((size_t)(b * 3 + jm) << 20) + row * HW + col) = o;
}

extern "C" void kernel_launch(void* const* d_in, const int* in_sizes, int n_in,
                              void* d_out, int out_size, void* d_ws, size_t ws_size,
                              hipStream_t stream) {
    const float* img = (const float*)d_in[0];
    float* out = (float*)d_out;
    float* ws = (float*)d_ws;

    float* csum = ws;                 // 8 floats
    int* grgc = (int*)(ws + 8);       // 24 ints
    float* cellmean = ws + 32;        // 8*3*182 floats
    float* stage = ws + 8192;         // 8M floats (32 MB) if available

    const size_t need = 8192 * sizeof(float) + (size_t)8 * PLANE * sizeof(float);
    const int do_stage = (ws_size >= need) ? 1 : 0;

    hipMemsetAsync(csum, 0, 8 * sizeof(float), stream);
    k_gray<<<dim3(1024, 8), 256, 0, stream>>>(img, csum, stage, do_stage);
    k_finalize<<<1, 64, 0, stream>>>(csum, out, grgc);
    k_cellmean<<<dim3(MAXCELL, 3, 8), 256, 0, stream>>>(img, stage, grgc, cellmean, do_stage);
    k_fill<<<dim3(1024, 3, 8), 256, 0, stream>>>(grgc, cellmean, out);
}

// Round 2
// 121.497 us; speedup vs baseline: 1.4269x; 1.4269x over previous
//
#include <hip/hip_runtime.h>
#include <math.h>

#define HW 1024
#define PLANE (1024 * 1024)
#define MAXCELL 182  // largest gr*gc over n in {20,30,40,65,80,95,125,150,175}

// ws layout (float units):
// [0..1024)     per-block GLCM partials (128 blocks/batch * 8 batches)
// [1024..1048)  packed gr|gc<<8 ints per (batch,map) - 24 entries
// [1056..5424)  cell means: 8 batches * 3 maps * 182 cells
// [8192 ..)     staged channel-mean image (8*1024*1024 floats) if ws_size permits

__device__ __forceinline__ int wave_reduce_int(int v) {
#pragma unroll
    for (int off = 32; off > 0; off >>= 1) v += __shfl_down(v, off, 64);
    return v;
}
__device__ __forceinline__ float wave_reduce_f(float v) {
#pragma unroll
    for (int off = 32; off > 0; off >>= 1) v += __shfl_down(v, off, 64);
    return v;
}

// Kernel 1: block = 8 rows of one batch (4 waves x 2 iterations; one wave owns
// one full row, lane owns 16 contiguous px). GLCM neighbor across lanes via
// shfl; NO atomics, NO shared-mem in hot path. Also stages channel-mean image.
__global__ __launch_bounds__(256) void k_gray(const float* __restrict__ img,
                                              float* __restrict__ partials,
                                              float* __restrict__ stage,
                                              int do_stage) {
    const int b = blockIdx.y;
    const int tid = threadIdx.x;
    const int lane = tid & 63;
    const int w = tid >> 6;
    const int row0 = blockIdx.x << 3;

    const float* base = img + (size_t)b * (3 * PLANE);
    float* stg = stage + ((size_t)b << 20);

    int acc = 0;
#pragma unroll
    for (int it = 0; it < 2; ++it) {
        const int row = row0 + (it << 2) + w;
        const int c0 = lane << 4;
        const float* p = base + row * HW + c0;
        float* sp = stg + row * HW + c0;

        int gi[16];
#pragma unroll
        for (int k = 0; k < 4; ++k) {
            const float4 R = *(const float4*)(p + (k << 2));
            const float4 G = *(const float4*)(p + PLANE + (k << 2));
            const float4 Bv = *(const float4*)(p + 2 * PLANE + (k << 2));

            const float g0 = 0.299f * R.x + 0.587f * G.x + 0.114f * Bv.x;
            const float g1 = 0.299f * R.y + 0.587f * G.y + 0.114f * Bv.y;
            const float g2 = 0.299f * R.z + 0.587f * G.z + 0.114f * Bv.z;
            const float g3 = 0.299f * R.w + 0.587f * G.w + 0.114f * Bv.w;

            gi[(k << 2) + 0] = min(max((int)(g0 * 255.0f), 0), 255);
            gi[(k << 2) + 1] = min(max((int)(g1 * 255.0f), 0), 255);
            gi[(k << 2) + 2] = min(max((int)(g2 * 255.0f), 0), 255);
            gi[(k << 2) + 3] = min(max((int)(g3 * 255.0f), 0), 255);

            if (do_stage) {
                float4 cm;
                cm.x = (R.x + G.x + Bv.x) * (1.0f / 3.0f);
                cm.y = (R.y + G.y + Bv.y) * (1.0f / 3.0f);
                cm.z = (R.z + G.z + Bv.z) * (1.0f / 3.0f);
                cm.w = (R.w + G.w + Bv.w) * (1.0f / 3.0f);
                *(float4*)(sp + (k << 2)) = cm;
            }
        }

        const int nxt = __shfl_down(gi[0], 1, 64);  // next lane's first gray idx
        int s = 0;
#pragma unroll
        for (int k = 0; k < 15; ++k) {
            const int d = gi[k] - gi[k + 1];
            s += d * d;
        }
        if (lane != 63) {
            const int d = gi[15] - nxt;
            s += d * d;
        }
        acc += s;
    }

    acc = wave_reduce_int(acc);  // exact int within block
    __shared__ int sw[4];
    if (lane == 0) sw[w] = acc;
    __syncthreads();
    if (tid == 0)
        partials[(b << 7) + blockIdx.x] = (float)(sw[0] + sw[1] + sw[2] + sw[3]);
}

// Kernel 2: reduce 128 partials/batch, finalize complexity, pick tier, emit
// cluster_sets (as float32 values into the f32 output buffer) + grid geometry.
__global__ void k_finalize(const float* __restrict__ partials,
                           float* __restrict__ out,
                           int* __restrict__ grgc) {
    const int t = threadIdx.x;  // 1024 threads = 16 waves; 2 waves per batch
    float v = partials[t];
    v = wave_reduce_f(v);
    __shared__ float sw[16];
    if ((t & 63) == 0) sw[t >> 6] = v;
    __syncthreads();
    if (t < 8) {
        const size_t OFFC = (size_t)8 * 3 * PLANE;
        float cv = (sw[2 * t] + sw[2 * t + 1]) * (1.0f / (1024.0f * 1023.0f));
        out[OFFC + t] = cv;
        int tier = (cv < 50.0f) ? 0 : ((cv < 150.0f) ? 1 : 2);
        const int BASEv[3] = {30, 80, 150};
        const int INCRv[3] = {10, 15, 25};
        int k = BASEv[tier], d = INCRv[tier];
#pragma unroll
        for (int j = 0; j < 3; ++j) {
            int n = k + (j - 1) * d;
            out[OFFC + 8 + t * 3 + j] = (float)n;
            int gr = (int)floor(sqrt((double)n) + 0.5);  // Python round(sqrt(n))
            if (gr < 1) gr = 1;
            int gc = (n + gr - 1) / gr;  // ceil(n/gr)
            grgc[t * 3 + j] = gr | (gc << 8);
        }
    }
}

// Kernel 3: one block per (cell, map, batch): mean of channel-mean over the
// cell's rectangle. Row-cell i covers rows [ceil(i*H/gr), ceil((i+1)*H/gr)).
__global__ __launch_bounds__(256) void k_cellmean(const float* __restrict__ img,
                                                  const float* __restrict__ stage,
                                                  const int* __restrict__ grgc,
                                                  float* __restrict__ cellmean,
                                                  int do_stage) {
    const int cell = blockIdx.x, jm = blockIdx.y, b = blockIdx.z;
    const int pk = grgc[b * 3 + jm];
    const int gr = pk & 255, gc = pk >> 8;
    if (cell >= gr * gc) return;
    const int ci = cell / gc, cj = cell - ci * gc;
    const int r0 = (ci * HW + gr - 1) / gr, r1 = ((ci + 1) * HW + gr - 1) / gr;
    const int c0 = (cj * HW + gc - 1) / gc, c1 = ((cj + 1) * HW + gc - 1) / gc;

    const int tid = threadIdx.x;
    const int tx = tid & 63, ty = tid >> 6;
    float s = 0.0f;
    if (do_stage) {
        const float* src = stage + ((size_t)b << 20);
        for (int r = r0 + ty; r < r1; r += 4)
            for (int c = c0 + tx; c < c1; c += 64) s += src[r * HW + c];
    } else {
        const float* src = img + (size_t)b * (3 * PLANE);
        for (int r = r0 + ty; r < r1; r += 4)
            for (int c = c0 + tx; c < c1; c += 64) {
                int idx = r * HW + c;
                s += (src[idx] + src[idx + PLANE] + src[idx + 2 * PLANE]) * (1.0f / 3.0f);
            }
    }
    s = wave_reduce_f(s);
    __shared__ float sw[4];
    const int lane = tid & 63, w = tid >> 6;
    if (lane == 0) sw[w] = s;
    __syncthreads();
    if (tid == 0) {
        float tot = sw[0] + sw[1] + sw[2] + sw[3];
        float area = (float)((r1 - r0) * (c1 - c0));
        cellmean[(b * 3 + jm) * MAXCELL + cell] = tot / area;
    }
}

// Kernel 4: fill saliency output; each thread writes a float4 of one row.
__global__ __launch_bounds__(256) void k_fill(const int* __restrict__ grgc,
                                              const float* __restrict__ cellmean,
                                              float* __restrict__ out) {
    const int row = blockIdx.x, jm = blockIdx.y, b = blockIdx.z;
    const int tid = threadIdx.x;
    const int pk = grgc[b * 3 + jm];
    const int gr = pk & 255, gc = pk >> 8;
    const int rc = (row * gr) >> 10;  // (row*gr)/1024
    const float* cm = cellmean + (b * 3 + jm) * MAXCELL + rc * gc;
    const int col = tid << 2;
    float4 o;
    o.x = cm[(col * gc) >> 10];
    o.y = cm[((col + 1) * gc) >> 10];
    o.z = cm[((col + 2) * gc) >> 10];
    o.w = cm[((col + 3) * gc) >> 10];
    *(float4*)(out + ((size_t)(b * 3 + jm) << 20) + row * HW + col) = o;
}

extern "C" void kernel_launch(void* const* d_in, const int* in_sizes, int n_in,
                              void* d_out, int out_size, void* d_ws, size_t ws_size,
                              hipStream_t stream) {
    const float* img = (const float*)d_in[0];
    float* out = (float*)d_out;
    float* ws = (float*)d_ws;

    float* partials = ws;                  // 1024 floats
    int* grgc = (int*)(ws + 1024);         // 24 ints
    float* cellmean = ws + 1056;           // 8*3*182 floats
    float* stage = ws + 8192;              // 8M floats (32 MB) if available

    const size_t need = 8192 * sizeof(float) + (size_t)8 * PLANE * sizeof(float);
    const int do_stage = (ws_size >= need) ? 1 : 0;

    k_gray<<<dim3(128, 8), 256, 0, stream>>>(img, partials, stage, do_stage);
    k_finalize<<<1, 1024, 0, stream>>>(partials, out, grgc);
    k_cellmean<<<dim3(MAXCELL, 3, 8), 256, 0, stream>>>(img, stage, grgc, cellmean, do_stage);
    k_fill<<<dim3(1024, 3, 8), 256, 0, stream>>>(grgc, cellmean, out);
}

// Round 3
// 79.322 us; speedup vs baseline: 2.1856x; 1.5317x over previous
//
#include <hip/hip_runtime.h>
#include <math.h>

#define HW 1024
#define PLANE (1024 * 1024)
#define MAXCELL 182  // largest gr*gc over n in {20,30,40,65,80,95,125,150,175}

// ws layout (float units):
// [0..2048)     per-block GLCM partials (256 blocks/batch * 8 batches)
// [2048..2072)  packed gr|gc<<8 ints per (batch,map) - 24 entries
// [2080..6448)  cell means: 8 batches * 3 maps * 182 cells
// [8192 ..)     staged channel-mean image (8*1024*1024 floats) if ws_size permits

__device__ __forceinline__ int wave_reduce_int(int v) {
#pragma unroll
    for (int off = 32; off > 0; off >>= 1) v += __shfl_down(v, off, 64);
    return v;
}
__device__ __forceinline__ float wave_reduce_f(float v) {
#pragma unroll
    for (int off = 32; off > 0; off >>= 1) v += __shfl_down(v, off, 64);
    return v;
}

// Kernel 1: grid (256, 8); block = 4 waves, one ROW per wave. Lane l owns
// float4 chunks #l, #l+64, #l+128, #l+192 of the row, so every global
// load/store instruction is a fully contiguous 1KB wave access (no strided
// holes -> no write-allocate fetch, no partial-line write amplification).
// GLCM seam between chunk #(j*64+63) and #(j*64+64): lane 63 defers its last
// diff one iteration and gets lane 0's first element via broadcast shfl.
__global__ __launch_bounds__(256) void k_gray(const float* __restrict__ img,
                                              float* __restrict__ partials,
                                              float* __restrict__ stage,
                                              int do_stage) {
    const int b = blockIdx.y;
    const int tid = threadIdx.x;
    const int lane = tid & 63;
    const int w = tid >> 6;
    const int row = (blockIdx.x << 2) + w;

    const float* p = img + (size_t)b * (3 * PLANE) + row * HW;
    float* sp = stage + ((size_t)b << 20) + row * HW;

    int s = 0;
    int pend = 0;
#pragma unroll
    for (int j = 0; j < 4; ++j) {
        const int c = ((j << 6) + lane) << 2;  // float offset of this lane's float4
        const float4 R = *(const float4*)(p + c);
        const float4 G = *(const float4*)(p + PLANE + c);
        const float4 Bv = *(const float4*)(p + 2 * PLANE + c);

        const float g0 = 0.299f * R.x + 0.587f * G.x + 0.114f * Bv.x;
        const float g1 = 0.299f * R.y + 0.587f * G.y + 0.114f * Bv.y;
        const float g2 = 0.299f * R.z + 0.587f * G.z + 0.114f * Bv.z;
        const float g3 = 0.299f * R.w + 0.587f * G.w + 0.114f * Bv.w;

        const int gi0 = min(max((int)(g0 * 255.0f), 0), 255);
        const int gi1 = min(max((int)(g1 * 255.0f), 0), 255);
        const int gi2 = min(max((int)(g2 * 255.0f), 0), 255);
        const int gi3 = min(max((int)(g3 * 255.0f), 0), 255);

        if (do_stage) {
            float4 cm;
            cm.x = (R.x + G.x + Bv.x) * (1.0f / 3.0f);
            cm.y = (R.y + G.y + Bv.y) * (1.0f / 3.0f);
            cm.z = (R.z + G.z + Bv.z) * (1.0f / 3.0f);
            cm.w = (R.w + G.w + Bv.w) * (1.0f / 3.0f);
            *(float4*)(sp + c) = cm;
        }

        const int first0 = __shfl(gi0, 0, 64);      // lane 0's first element
        if (j > 0 && lane == 63) {
            const int d = pend - first0;            // seam: chunk 63 -> chunk 64
            s += d * d;
        }
        const int nxt = __shfl_down(gi0, 1, 64);    // next lane's first element
        const int d0 = gi0 - gi1, d1 = gi1 - gi2, d2 = gi2 - gi3;
        s += d0 * d0 + d1 * d1 + d2 * d2;
        if (lane != 63) {
            const int d = gi3 - nxt;
            s += d * d;
        }
        pend = gi3;  // last element; at j==3 this is col 1023 (no neighbor)
    }

    s = wave_reduce_int(s);  // exact int within block
    __shared__ int sw[4];
    if (lane == 0) sw[w] = s;
    __syncthreads();
    if (tid == 0)
        partials[(b << 8) + blockIdx.x] = (float)(sw[0] + sw[1] + sw[2] + sw[3]);
}

// Kernel 2: reduce 256 partials/batch, finalize complexity, pick tier, emit
// cluster_sets (as float32 values into the f32 output buffer) + grid geometry.
__global__ void k_finalize(const float* __restrict__ partials,
                           float* __restrict__ out,
                           int* __restrict__ grgc) {
    const int t = threadIdx.x;  // 1024 threads = 16 waves; 2 waves per batch
    float v = partials[2 * t] + partials[2 * t + 1];
    v = wave_reduce_f(v);
    __shared__ float sw[16];
    if ((t & 63) == 0) sw[t >> 6] = v;
    __syncthreads();
    if (t < 8) {
        const size_t OFFC = (size_t)8 * 3 * PLANE;
        float cv = (sw[2 * t] + sw[2 * t + 1]) * (1.0f / (1024.0f * 1023.0f));
        out[OFFC + t] = cv;
        int tier = (cv < 50.0f) ? 0 : ((cv < 150.0f) ? 1 : 2);
        const int BASEv[3] = {30, 80, 150};
        const int INCRv[3] = {10, 15, 25};
        int k = BASEv[tier], d = INCRv[tier];
#pragma unroll
        for (int j = 0; j < 3; ++j) {
            int n = k + (j - 1) * d;
            out[OFFC + 8 + t * 3 + j] = (float)n;
            int gr = (int)floor(sqrt((double)n) + 0.5);  // Python round(sqrt(n))
            if (gr < 1) gr = 1;
            int gc = (n + gr - 1) / gr;  // ceil(n/gr)
            grgc[t * 3 + j] = gr | (gc << 8);
        }
    }
}

// Kernel 3: one block per (cell, map, batch): mean of channel-mean over the
// cell's rectangle. Row-cell i covers rows [ceil(i*H/gr), ceil((i+1)*H/gr)).
__global__ __launch_bounds__(256) void k_cellmean(const float* __restrict__ img,
                                                  const float* __restrict__ stage,
                                                  const int* __restrict__ grgc,
                                                  float* __restrict__ cellmean,
                                                  int do_stage) {
    const int cell = blockIdx.x, jm = blockIdx.y, b = blockIdx.z;
    const int pk = grgc[b * 3 + jm];
    const int gr = pk & 255, gc = pk >> 8;
    if (cell >= gr * gc) return;
    const int ci = cell / gc, cj = cell - ci * gc;
    const int r0 = (ci * HW + gr - 1) / gr, r1 = ((ci + 1) * HW + gr - 1) / gr;
    const int c0 = (cj * HW + gc - 1) / gc, c1 = ((cj + 1) * HW + gc - 1) / gc;

    const int tid = threadIdx.x;
    const int tx = tid & 63, ty = tid >> 6;
    float s = 0.0f;
    if (do_stage) {
        const float* src = stage + ((size_t)b << 20);
        for (int r = r0 + ty; r < r1; r += 4)
            for (int c = c0 + tx; c < c1; c += 64) s += src[r * HW + c];
    } else {
        const float* src = img + (size_t)b * (3 * PLANE);
        for (int r = r0 + ty; r < r1; r += 4)
            for (int c = c0 + tx; c < c1; c += 64) {
                int idx = r * HW + c;
                s += (src[idx] + src[idx + PLANE] + src[idx + 2 * PLANE]) * (1.0f / 3.0f);
            }
    }
    s = wave_reduce_f(s);
    __shared__ float sw[4];
    const int lane = tid & 63, w = tid >> 6;
    if (lane == 0) sw[w] = s;
    __syncthreads();
    if (tid == 0) {
        float tot = sw[0] + sw[1] + sw[2] + sw[3];
        float area = (float)((r1 - r0) * (c1 - c0));
        cellmean[(b * 3 + jm) * MAXCELL + cell] = tot / area;
    }
}

// Kernel 4: fill saliency output; each thread writes a float4 of one row.
__global__ __launch_bounds__(256) void k_fill(const int* __restrict__ grgc,
                                              const float* __restrict__ cellmean,
                                              float* __restrict__ out) {
    const int row = blockIdx.x, jm = blockIdx.y, b = blockIdx.z;
    const int tid = threadIdx.x;
    const int pk = grgc[b * 3 + jm];
    const int gr = pk & 255, gc = pk >> 8;
    const int rc = (row * gr) >> 10;  // (row*gr)/1024
    const float* cm = cellmean + (b * 3 + jm) * MAXCELL + rc * gc;
    const int col = tid << 2;
    float4 o;
    o.x = cm[(col * gc) >> 10];
    o.y = cm[((col + 1) * gc) >> 10];
    o.z = cm[((col + 2) * gc) >> 10];
    o.w = cm[((col + 3) * gc) >> 10];
    *(float4*)(out + ((size_t)(b * 3 + jm) << 20) + row * HW + col) = o;
}

extern "C" void kernel_launch(void* const* d_in, const int* in_sizes, int n_in,
                              void* d_out, int out_size, void* d_ws, size_t ws_size,
                              hipStream_t stream) {
    const float* img = (const float*)d_in[0];
    float* out = (float*)d_out;
    float* ws = (float*)d_ws;

    float* partials = ws;                  // 2048 floats
    int* grgc = (int*)(ws + 2048);         // 24 ints
    float* cellmean = ws + 2080;           // 8*3*182 floats
    float* stage = ws + 8192;              // 8M floats (32 MB) if available

    const size_t need = 8192 * sizeof(float) + (size_t)8 * PLANE * sizeof(float);
    const int do_stage = (ws_size >= need) ? 1 : 0;

    k_gray<<<dim3(256, 8), 256, 0, stream>>>(img, partials, stage, do_stage);
    k_finalize<<<1, 1024, 0, stream>>>(partials, out, grgc);
    k_cellmean<<<dim3(MAXCELL, 3, 8), 256, 0, stream>>>(img, stage, grgc, cellmean, do_stage);
    k_fill<<<dim3(1024, 3, 8), 256, 0, stream>>>(grgc, cellmean, out);
}

// Round 4
// 46.896 us; speedup vs baseline: 3.6968x; 1.6914x over previous
//
#include <hip/hip_runtime.h>
#include <math.h>

#define HW 1024
#define PLANE (1024 * 1024)

// 9 possible grids (n in {20,30,40,65,80,95,125,150,175}), all compile-time:
//   g:      0    1    2    3    4    5    6    7    8
//   n:     20   30   40   65   80   95  125  150  175
//   gr:     4    5    6    8    9   10   11   12   13
//   gc:     5    6    7    9    9   10   12   13   14
// Unique column structures (gc): {5,6,7,9,10,12,13,14} -> 8 structures,
// 76 total col-cells, 84 total boundary entries (incl. 0 and 1024).
__constant__ int GCS[8]   = {5, 6, 7, 9, 10, 12, 13, 14};
__constant__ int BBASE[8] = {0, 6, 13, 21, 31, 42, 55, 69};   // boundary-entry base (gc+1 each)
__constant__ int GR9c[9]      = {4, 5, 6, 8, 9, 10, 11, 12, 13};
__constant__ int GC9c[9]      = {5, 6, 7, 9, 9, 10, 12, 13, 14};
__constant__ int GBASE9c[9]   = {0, 20, 50, 92, 164, 245, 345, 477, 633};  // cumsum gr*gc (total 815)
__constant__ int COLBASE9c[9] = {0, 5, 11, 18, 18, 27, 37, 49, 62};        // col-structure base per grid

// ws layout (float units):
// [0..2048)        per-block GLCM partials (256 blocks/batch * 8 batches)
// [2048..2056)     tier per batch (int)
// [2080..8600)     cellmean for ALL 9 grids: 8 batches * 815 cells
// [16384..671744)  per-row column-cell records: 8 * 1024 rows * 80 (76 used)

__device__ __forceinline__ int wave_reduce_int(int v) {
#pragma unroll
    for (int off = 32; off > 0; off >>= 1) v += __shfl_down(v, off, 64);
    return v;
}

// Kernel 1: grid (256, 8); 4 waves/block, one ROW per wave. Lane l owns float4
// chunks #l, #l+64, #l+128, #l+192 (every global load is a contiguous 1KB wave
// access). Produces: (a) GLCM squared-diff block partials, (b) per-row sums of
// the channel-mean image over every column-cell of all 8 unique structures,
// via per-chunk sums -> wave scan -> boundary prefix differences (boundary
// columns are compile-time derivable; LDS holds per-row cm + prefixes).
__global__ __launch_bounds__(256) void k_main(const float* __restrict__ img,
                                              float* __restrict__ partials,
                                              float* __restrict__ rowrec) {
    const int b = blockIdx.y;
    const int tid = threadIdx.x;
    const int lane = tid & 63;
    const int w = tid >> 6;
    const int row = (blockIdx.x << 2) + w;

    const float* p = img + (size_t)b * (3 * PLANE) + row * HW;

    __shared__ float cmS[4][1024];  // per-row channel-mean
    __shared__ float PS[4][260];    // per-row exclusive prefix at chunk granularity (+ total at [256])
    __shared__ float BS[4][88];     // per-row boundary prefix values (84 used)
    __shared__ int swred[4];

    int acc = 0;
    int pend = 0;
    float csum[4];

#pragma unroll
    for (int j = 0; j < 4; ++j) {
        const int c = ((j << 6) + lane) << 2;
        const float4 R = *(const float4*)(p + c);
        const float4 G = *(const float4*)(p + PLANE + c);
        const float4 Bv = *(const float4*)(p + 2 * PLANE + c);

        const float m0 = (R.x + G.x + Bv.x) * (1.0f / 3.0f);
        const float m1 = (R.y + G.y + Bv.y) * (1.0f / 3.0f);
        const float m2 = (R.z + G.z + Bv.z) * (1.0f / 3.0f);
        const float m3 = (R.w + G.w + Bv.w) * (1.0f / 3.0f);
        *(float4*)&cmS[w][c] = make_float4(m0, m1, m2, m3);
        csum[j] = (m0 + m1) + (m2 + m3);

        const float g0 = 0.299f * R.x + 0.587f * G.x + 0.114f * Bv.x;
        const float g1 = 0.299f * R.y + 0.587f * G.y + 0.114f * Bv.y;
        const float g2 = 0.299f * R.z + 0.587f * G.z + 0.114f * Bv.z;
        const float g3 = 0.299f * R.w + 0.587f * G.w + 0.114f * Bv.w;

        const int gi0 = min(max((int)(g0 * 255.0f), 0), 255);
        const int gi1 = min(max((int)(g1 * 255.0f), 0), 255);
        const int gi2 = min(max((int)(g2 * 255.0f), 0), 255);
        const int gi3 = min(max((int)(g3 * 255.0f), 0), 255);

        const int first0 = __shfl(gi0, 0, 64);      // lane 0's first element
        if (j > 0 && lane == 63) {
            const int d = pend - first0;            // seam: chunk 63 -> chunk 64
            acc += d * d;
        }
        const int nxt = __shfl_down(gi0, 1, 64);    // next lane's first element
        const int d0 = gi0 - gi1, d1 = gi1 - gi2, d2 = gi2 - gi3;
        acc += d0 * d0 + d1 * d1 + d2 * d2;
        if (lane != 63) {
            const int d = gi3 - nxt;
            acc += d * d;
        }
        pend = gi3;
    }

    // Wave scans: exclusive prefix of chunk sums over the whole row.
    float pre = 0.0f;
#pragma unroll
    for (int j = 0; j < 4; ++j) {
        float x = csum[j];
#pragma unroll
        for (int off = 1; off < 64; off <<= 1) {
            const float y = __shfl_up(x, off, 64);
            if (lane >= off) x += y;
        }
        PS[w][(j << 6) + lane] = pre + (x - csum[j]);  // exclusive prefix of chunk (j*64+lane)
        pre += __shfl(x, 63, 64);
    }
    if (lane == 0) PS[w][256] = pre;  // row total (boundary col 1024)

    // Boundary prefixes B(c) for all 84 boundary entries (wave-local LDS).
#pragma unroll
    for (int rep = 0; rep < 2; ++rep) {
        const int bnd = lane + (rep << 6);
        if (bnd < 84) {
            const int sct = (bnd >= 6) + (bnd >= 13) + (bnd >= 21) + (bnd >= 31) +
                            (bnd >= 42) + (bnd >= 55) + (bnd >= 69);
            const int gc = GCS[sct];
            const int i = bnd - BBASE[sct];
            const int c = (i * 1024 + gc - 1) / gc;  // ceil(i*1024/gc), compile-consistent with labels
            const int m = c & 3;
            const int cb = min(c & ~3, 1020);        // clamp for c==1024 (m==0, adds skipped)
            float Bp = PS[w][c >> 2];
            const float a0 = cmS[w][cb], a1 = cmS[w][cb + 1], a2 = cmS[w][cb + 2];
            if (m > 0) Bp += a0;
            if (m > 1) Bp += a1;
            if (m > 2) Bp += a2;
            BS[w][bnd] = Bp;
        }
    }

    // Column-cell sums = adjacent boundary differences -> per-row record.
    float* rr = rowrec + (size_t)((b << 10) + row) * 80;
#pragma unroll
    for (int rep = 0; rep < 2; ++rep) {
        const int k = lane + (rep << 6);
        if (k < 76) {
            const int sct = (k >= 5) + (k >= 11) + (k >= 18) + (k >= 27) +
                            (k >= 37) + (k >= 49) + (k >= 62);
            const int bidx = k + sct;
            rr[k] = BS[w][bidx + 1] - BS[w][bidx];
        }
    }

    acc = wave_reduce_int(acc);  // exact int within block
    if (lane == 0) swred[w] = acc;
    __syncthreads();
    if (tid == 0)
        partials[(b << 8) + blockIdx.x] = (float)(swred[0] + swred[1] + swred[2] + swred[3]);
}

// Kernel 2: grid (13, 9, 8): block (rc, g, b) reduces rows of row-cell rc for
// grid g -> cell means (all 9 grids, independent of tier). Block (0,0,0) also
// finalizes complexity, writes complexity + cluster_sets outputs and tier[].
__global__ __launch_bounds__(256) void k_reduce(const float* __restrict__ rowrec,
                                                const float* __restrict__ partials,
                                                float* __restrict__ cellmean,
                                                float* __restrict__ out,
                                                int* __restrict__ tier_ws) {
    const int rc = blockIdx.x, g = blockIdx.y, b = blockIdx.z;
    const int t = threadIdx.x;
    const int gr = GR9c[g];
    const bool active = (rc < gr);

    __shared__ float red[16][17];
    __shared__ float compLDS[8];

    const int gc = GC9c[g];
    const int cb = COLBASE9c[g];
    const int r0 = (rc * 1024 + gr - 1) / gr;
    const int r1 = ((rc + 1) * 1024 + gr - 1) / gr;
    const int cc = t & 15, rch = t >> 4;

    if (active) {
        float s = 0.0f;
        if (cc < gc)
            for (int r = r0 + rch; r < r1; r += 16)
                s += rowrec[(size_t)((b << 10) + r) * 80 + cb + cc];
        red[rch][cc] = s;
    }

    const bool special = (rc == 0 && g == 0 && b == 0);
    if (special) {
        const int b2 = t >> 5, sub = t & 31;
        float sC = 0.0f;
#pragma unroll
        for (int kk = 0; kk < 8; ++kk) sC += partials[(b2 << 8) + sub + (kk << 5)];
#pragma unroll
        for (int off = 16; off > 0; off >>= 1) sC += __shfl_down(sC, off, 32);
        if (sub == 0) compLDS[b2] = sC;
    }

    __syncthreads();

    if (active && rch == 0 && cc < gc) {
        float tot = 0.0f;
#pragma unroll
        for (int q = 0; q < 16; ++q) tot += red[q][cc];
        const int c0 = (cc * 1024 + gc - 1) / gc;
        const int c1 = ((cc + 1) * 1024 + gc - 1) / gc;
        const float area = (float)((r1 - r0) * (c1 - c0));
        cellmean[b * 815 + GBASE9c[g] + rc * gc + cc] = tot / area;
    }

    if (special && t < 8) {
        const size_t OFFC = (size_t)8 * 3 * PLANE;
        const float cv = compLDS[t] * (1.0f / (1024.0f * 1023.0f));
        out[OFFC + t] = cv;
        const int tier = (cv < 50.0f) ? 0 : ((cv < 150.0f) ? 1 : 2);
        const int kk = (tier == 0) ? 30 : ((tier == 1) ? 80 : 150);
        const int dd = (tier == 0) ? 10 : ((tier == 1) ? 15 : 25);
#pragma unroll
        for (int j = 0; j < 3; ++j)
            out[OFFC + 8 + t * 3 + j] = (float)(kk + (j - 1) * dd);  // int32 values, f32 buffer
        tier_ws[t] = tier;
    }
}

// Kernel 3: fill saliency; grid index is tier*3 + map (cluster-set order).
__global__ __launch_bounds__(256) void k_fill(const int* __restrict__ tier_ws,
                                              const float* __restrict__ cellmean,
                                              float* __restrict__ out) {
    const int row = blockIdx.x, jm = blockIdx.y, b = blockIdx.z;
    const int tid = threadIdx.x;
    const int g = tier_ws[b] * 3 + jm;
    const int gr = GR9c[g], gc = GC9c[g];
    const int rc = (row * gr) >> 10;
    const float* cm = cellmean + b * 815 + GBASE9c[g] + rc * gc;
    const int col = tid << 2;
    float4 o;
    o.x = cm[(col * gc) >> 10];
    o.y = cm[((col + 1) * gc) >> 10];
    o.z = cm[((col + 2) * gc) >> 10];
    o.w = cm[((col + 3) * gc) >> 10];
    *(float4*)(out + ((size_t)(b * 3 + jm) << 20) + row * HW + col) = o;
}

extern "C" void kernel_launch(void* const* d_in, const int* in_sizes, int n_in,
                              void* d_out, int out_size, void* d_ws, size_t ws_size,
                              hipStream_t stream) {
    const float* img = (const float*)d_in[0];
    float* out = (float*)d_out;
    float* ws = (float*)d_ws;

    float* partials = ws;              // 2048 floats
    int* tier_ws = (int*)(ws + 2048);  // 8 ints
    float* cellmean = ws + 2080;       // 8*815 floats
    float* rowrec = ws + 16384;        // 8*1024*80 floats (2.6 MB)

    k_main<<<dim3(256, 8), 256, 0, stream>>>(img, partials, rowrec);
    k_reduce<<<dim3(13, 9, 8), 256, 0, stream>>>(rowrec, partials, cellmean, out, tier_ws);
    k_fill<<<dim3(1024, 3, 8), 256, 0, stream>>>(tier_ws, cellmean, out);
}